// Round 5
// baseline (598.439 us; speedup 1.0000x reference)
//
#include <hip/hip_runtime.h>

// B=16, LQ=LP=2048, H=1024
//   q_lin = relu(q @ W^T + b); p_lin = relu(p @ W^T + b)
//   scores = p_lin @ q_lin^T ; att = softmax(scores); out = att @ q_lin
// GEMMs: 256x256 tile, BK=64, 8 waves, 8-phase schedule, fp16 MFMA 16x16x32.
// LDS swizzle: addr ^= (row&7)<<4. q_linT via dedicated tiled transpose kernel
// (round-4 fix: transposed epilogue writes caused 134MB of RMW HBM fetch).

#define LQN 2048
#define LPN 2048
#define HD  1024
#define NBATCH 16

typedef _Float16 half8 __attribute__((ext_vector_type(8)));
typedef _Float16 half4_t __attribute__((ext_vector_type(4)));
typedef float f32x4 __attribute__((ext_vector_type(4)));

#define GLP(src, dst) __builtin_amdgcn_global_load_lds(                          \
    (const __attribute__((address_space(1))) void*)(src),                        \
    (__attribute__((address_space(3))) void*)(dst), 16, 0, 0)

// ---------------------------------------------------------------- convert f32->f16
__global__ __launch_bounds__(256) void cvt_f32_f16(const float* __restrict__ in,
                                                   _Float16* __restrict__ out,
                                                   long n4) {
  long i0 = (long)blockIdx.x * blockDim.x + threadIdx.x;
  long stride = (long)gridDim.x * blockDim.x;
  for (long i = i0; i < n4; i += stride) {
    float4 v = ((const float4*)in)[i];
    half4_t h = {(_Float16)v.x, (_Float16)v.y, (_Float16)v.z, (_Float16)v.w};
    ((half4_t*)out)[i] = h;
  }
}

// ---------------------------------------------------------------- tiled transpose
// in: [16][2048][1024] fp16 -> out: [16][1024][2048] fp16. 64x64 tiles.
// LDS granule-XOR swizzle -> conflict-light, 16B coalesced global both sides.
__global__ __launch_bounds__(256) void transpose_k(const _Float16* __restrict__ in,
                                                   _Float16* __restrict__ out) {
  __shared__ _Float16 t[64][72];  // row stride 144B (16B-aligned)
  const int bz = blockIdx.z;
  const int q0 = blockIdx.x * 64;
  const int d0 = blockIdx.y * 64;
  const int tt = threadIdx.x;
  const int ql = tt & 63, dg = tt >> 6;  // load: row q, 16-half granule pair
  const _Float16* src = in + ((size_t)bz * LQN + q0 + ql) * HD + d0 + dg * 16;
  half8 v0 = *(const half8*)(src);
  half8 v1 = *(const half8*)(src + 8);
  int g0 = (dg * 2) ^ (ql & 7);
  int g1 = (dg * 2 + 1) ^ (ql & 7);
  *(half8*)&t[ql][g0 * 8] = v0;
  *(half8*)&t[ql][g1 * 8] = v1;
  __syncthreads();
  const int dl = tt & 63, qg = tt >> 6;  // store: row d, 16 q per thread
  half8 o0, o1;
#pragma unroll
  for (int j = 0; j < 8; ++j) {
    int qq = qg * 16 + j;
    o0[j] = t[qq][(((dl >> 3) ^ (qq & 7)) << 3) + (dl & 7)];
  }
#pragma unroll
  for (int j = 0; j < 8; ++j) {
    int qq = qg * 16 + 8 + j;
    o1[j] = t[qq][(((dl >> 3) ^ (qq & 7)) << 3) + (dl & 7)];
  }
  _Float16* dst = out + ((size_t)bz * HD + d0 + dl) * LQN + q0 + qg * 16;
  *(half8*)dst = o0;
  *(half8*)(dst + 8) = o1;
}

// ---------------------------------------------------------------- 8-phase 256^2 GEMM
// EPI 0: f32 C.  EPI 1: fp16 C = relu(acc+bias).

#define SYNC_PRE                                        \
  __builtin_amdgcn_sched_barrier(0);                    \
  __builtin_amdgcn_s_barrier();                         \
  asm volatile("s_waitcnt lgkmcnt(0)" ::: "memory");    \
  __builtin_amdgcn_sched_barrier(0);                    \
  __builtin_amdgcn_s_setprio(1);

#define SYNC_POST                                       \
  __builtin_amdgcn_s_setprio(0);                        \
  __builtin_amdgcn_sched_barrier(0);                    \
  __builtin_amdgcn_s_barrier();

#define SYNC_POST_VM                                    \
  __builtin_amdgcn_s_setprio(0);                        \
  __builtin_amdgcn_sched_barrier(0);                    \
  asm volatile("s_waitcnt vmcnt(4)" ::: "memory");      \
  __builtin_amdgcn_s_barrier();

#define LOADA(qm, buf)                                                            \
  _Pragma("unroll")                                                               \
  for (int mi = 0; mi < 4; ++mi) {                                                \
    areg[mi][0] = *(const half8*)(smA + (buf)*32768 + a0 + ((qm)*4+mi)*4096);     \
    areg[mi][1] = *(const half8*)(smA + (buf)*32768 + a1 + ((qm)*4+mi)*4096);     \
  }

#define LOADB(qn, buf)                                                            \
  _Pragma("unroll")                                                               \
  for (int ni = 0; ni < 2; ++ni) {                                                \
    bregs[qn][ni][0] = *(const half8*)(smB + (buf)*32768 + b0 + ((qn)*2+ni)*8192);\
    bregs[qn][ni][1] = *(const half8*)(smB + (buf)*32768 + b1 + ((qn)*2+ni)*8192);\
  }

#define STAGEA(t, h, buf) do {                                                    \
  GLP(gA + (size_t)((h)*128)*lda + (size_t)(t)*64,                                \
      smW + (buf)*32768 + (h)*16384 + wid*1024);                                  \
  GLP(gA + (size_t)((h)*128+64)*lda + (size_t)(t)*64,                             \
      smW + (buf)*32768 + (h)*16384 + 8192 + wid*1024);                           \
} while (0)

#define STAGEB(t, h, buf) do {                                                    \
  GLP(gB + (size_t)((h)*128)*ldb + (size_t)(t)*64,                                \
      smW + 65536 + (buf)*32768 + (h)*16384 + wid*1024);                          \
  GLP(gB + (size_t)((h)*128+64)*ldb + (size_t)(t)*64,                             \
      smW + 65536 + (buf)*32768 + (h)*16384 + 8192 + wid*1024);                   \
} while (0)

#define DO_MFMA(qm, qn)                                                           \
  _Pragma("unroll")                                                               \
  for (int mi = 0; mi < 4; ++mi) {                                                \
    _Pragma("unroll")                                                             \
    for (int ni = 0; ni < 2; ++ni) {                                              \
      acc[(qm)*4+mi][(qn)*2+ni] = __builtin_amdgcn_mfma_f32_16x16x32_f16(         \
          areg[mi][0], bregs[qn][ni][0], acc[(qm)*4+mi][(qn)*2+ni], 0, 0, 0);     \
      acc[(qm)*4+mi][(qn)*2+ni] = __builtin_amdgcn_mfma_f32_16x16x32_f16(         \
          areg[mi][1], bregs[qn][ni][1], acc[(qm)*4+mi][(qn)*2+ni], 0, 0, 0);     \
    }                                                                             \
  }

template <int EPI>
__global__ __launch_bounds__(512, 2) void gemm8p(
    const _Float16* __restrict__ A, const _Float16* __restrict__ B,
    const float* __restrict__ bias, void* __restrict__ Cv,
    int K, int lda, int ldb, int ldc,
    long sAz, long sBz, long sCz) {
  extern __shared__ __align__(16) char smem[];
  const char* smA = smem;            // A tiles: 2 x 32KB
  const char* smB = smem + 65536;    // B tiles: 2 x 32KB
  char* smW = smem;

  const int tid = threadIdx.x;
  const int lane = tid & 63, wid = tid >> 6;
  const int l16 = lane & 15, lhi = lane >> 4;
  const int wr = wid >> 2, wcn = wid & 3;

  // full-spread swizzle: flip 16B-slot bits 4-6 by row bits 0-2
  const int mask = (l16 & 7) << 4;
  const int a0 = (wr * 2048 + l16 * 128 + lhi * 16) ^ mask;
  const int a1 = a0 ^ 64;
  const int b0 = (wcn * 2048 + l16 * 128 + lhi * 16) ^ mask;
  const int b1 = b0 ^ 64;

  // inverse-swizzled staging source coords (same involution both sides)
  const int srow = tid >> 3;
  const int scol = (((tid & 7) ^ ((tid >> 3) & 7)) << 3);

  const int bm0 = blockIdx.x * 256, bn0 = blockIdx.y * 256;
  const _Float16* gA = A + (size_t)blockIdx.z * sAz + (size_t)(bm0 + srow) * lda + scol;
  const _Float16* gB = B + (size_t)blockIdx.z * sBz + (size_t)(bn0 + srow) * ldb + scol;

  const int NT = K >> 6, NI = K >> 7;

  f32x4 acc[8][4] = {};
  half8 areg[4][2], bregs[2][2][2];

  // prologue: tile0 (4 halves) + tile1 (h0 of A and B)
  STAGEA(0, 0, 0); STAGEB(0, 0, 0);
  STAGEA(0, 1, 0); STAGEB(0, 1, 0);
  STAGEA(1, 0, 1); STAGEB(1, 0, 1);
  __builtin_amdgcn_sched_barrier(0);
  asm volatile("s_waitcnt vmcnt(4)" ::: "memory");
  __builtin_amdgcn_s_barrier();

  for (int i = 0; i < NI; ++i) {
    const int t1 = 2 * i + 1;
    int t2 = 2 * i + 2; if (t2 > NT - 1) t2 = NT - 1;
    int t3 = 2 * i + 3; if (t3 > NT - 1) t3 = NT - 1;
    // ph1
    LOADA(0, 0) LOADB(0, 0) STAGEA(t1, 1, 1);
    SYNC_PRE DO_MFMA(0, 0) SYNC_POST
    // ph2
    LOADB(1, 0) STAGEB(t1, 1, 1);
    SYNC_PRE DO_MFMA(0, 1) SYNC_POST
    // ph3  (B qn=0 resident in bregs[0])
    LOADA(1, 0) STAGEA(t2, 0, 0);
    SYNC_PRE DO_MFMA(1, 0) SYNC_POST
    // ph4  (B qn=1 resident)
    STAGEB(t2, 0, 0);
    SYNC_PRE DO_MFMA(1, 1) SYNC_POST_VM
    // ph5
    LOADA(0, 1) LOADB(0, 1) STAGEA(t2, 1, 0);
    SYNC_PRE DO_MFMA(0, 0) SYNC_POST
    // ph6
    LOADB(1, 1) STAGEB(t2, 1, 0);
    SYNC_PRE DO_MFMA(0, 1) SYNC_POST
    // ph7
    LOADA(1, 1) STAGEA(t3, 0, 1);
    SYNC_PRE DO_MFMA(1, 0) SYNC_POST
    // ph8
    STAGEB(t3, 0, 1);
    SYNC_PRE DO_MFMA(1, 1) SYNC_POST_VM
  }

  // epilogue
  if constexpr (EPI == 0) {
    float* Cb = (float*)Cv + (size_t)blockIdx.z * sCz;
#pragma unroll
    for (int m = 0; m < 8; ++m) {
      int row0 = bm0 + m * 32 + wr * 16 + lhi * 4;
#pragma unroll
      for (int n = 0; n < 4; ++n) {
        int col = bn0 + n * 64 + wcn * 16 + l16;
#pragma unroll
        for (int v = 0; v < 4; ++v)
          Cb[(size_t)(row0 + v) * ldc + col] = acc[m][n][v];
      }
    }
  } else {
    _Float16* Cb = (_Float16*)Cv;
#pragma unroll
    for (int n = 0; n < 4; ++n) {
      int col = bn0 + n * 64 + wcn * 16 + l16;
      float bv = bias[col];
#pragma unroll
      for (int m = 0; m < 8; ++m) {
        int row0 = bm0 + m * 32 + wr * 16 + lhi * 4;
        Cb[(size_t)(row0 + 0) * ldc + col] = (_Float16)fmaxf(acc[m][n][0] + bv, 0.f);
        Cb[(size_t)(row0 + 1) * ldc + col] = (_Float16)fmaxf(acc[m][n][1] + bv, 0.f);
        Cb[(size_t)(row0 + 2) * ldc + col] = (_Float16)fmaxf(acc[m][n][2] + bv, 0.f);
        Cb[(size_t)(row0 + 3) * ldc + col] = (_Float16)fmaxf(acc[m][n][3] + bv, 0.f);
      }
    }
  }
}

// ---------------------------------------------------------------- row softmax, in-place f32->fp16
__global__ __launch_bounds__(256) void softmax_k(float* __restrict__ buf) {
  __shared__ float red[4];
  const int t = threadIdx.x;
  float* s = buf + (size_t)blockIdx.x * 2048;
  float4 v0 = ((const float4*)s)[t * 2];
  float4 v1 = ((const float4*)s)[t * 2 + 1];
  float m = fmaxf(fmaxf(fmaxf(v0.x, v0.y), fmaxf(v0.z, v0.w)),
                  fmaxf(fmaxf(v1.x, v1.y), fmaxf(v1.z, v1.w)));
#pragma unroll
  for (int o = 32; o; o >>= 1) m = fmaxf(m, __shfl_xor(m, o));
  if ((t & 63) == 0) red[t >> 6] = m;
  __syncthreads();
  m = fmaxf(fmaxf(red[0], red[1]), fmaxf(red[2], red[3]));
  float e[8];
  e[0] = __expf(v0.x - m); e[1] = __expf(v0.y - m);
  e[2] = __expf(v0.z - m); e[3] = __expf(v0.w - m);
  e[4] = __expf(v1.x - m); e[5] = __expf(v1.y - m);
  e[6] = __expf(v1.z - m); e[7] = __expf(v1.w - m);
  float sum = ((e[0] + e[1]) + (e[2] + e[3])) + ((e[4] + e[5]) + (e[6] + e[7]));
#pragma unroll
  for (int o = 32; o; o >>= 1) sum += __shfl_xor(sum, o);
  __syncthreads();
  if ((t & 63) == 0) red[t >> 6] = sum;
  __syncthreads();
  sum = (red[0] + red[1]) + (red[2] + red[3]);
  float inv = 1.f / sum;
  half8 h;
  h[0] = (_Float16)(e[0] * inv); h[1] = (_Float16)(e[1] * inv);
  h[2] = (_Float16)(e[2] * inv); h[3] = (_Float16)(e[3] * inv);
  h[4] = (_Float16)(e[4] * inv); h[5] = (_Float16)(e[5] * inv);
  h[6] = (_Float16)(e[6] * inv); h[7] = (_Float16)(e[7] * inv);
  ((half8*)s)[t] = h;
}

// ---------------------------------------------------------------- launch
extern "C" void kernel_launch(void* const* d_in, const int* in_sizes, int n_in,
                              void* d_out, int out_size, void* d_ws, size_t ws_size,
                              hipStream_t stream) {
  const float* q = (const float*)d_in[0];
  const float* p = (const float*)d_in[1];
  const float* W = (const float*)d_in[2];
  const float* bias = (const float*)d_in[3];
  float* out = (float*)d_out;
  char* ws = (char*)d_ws;

  // ws layout: [0,128MB) scratch (q_f16+p_f16, later scores chunk), then
  // q_lin(64MB), p_lin(64MB) [contiguous M=65536], q_linT(64MB), W_f16(2MB).
  _Float16* qf    = (_Float16*)(ws);
  _Float16* pf    = (_Float16*)(ws + 67108864L);
  _Float16* qlin  = (_Float16*)(ws + 134217728L);
  _Float16* plin  = (_Float16*)(ws + 201326592L);
  _Float16* qlinT = (_Float16*)(ws + 268435456L);
  _Float16* Wf    = (_Float16*)(ws + 335544320L);
  float* scores   = (float*)ws;

  const long nQ = (long)NBATCH * LQN * HD;
  const size_t SH = 131072;

  cvt_f32_f16<<<2048, 256, 0, stream>>>(q, qf, nQ / 4);
  cvt_f32_f16<<<2048, 256, 0, stream>>>(p, pf, nQ / 4);
  cvt_f32_f16<<<64, 256, 0, stream>>>(W, Wf, (long)HD * HD / 4);

  // fused shared linear + relu over q|p (M=65536)
  gemm8p<1><<<dim3(2 * NBATCH * LQN / 256, HD / 256, 1), 512, SH, stream>>>(
      qf, Wf, bias, qlin, HD, HD, HD, HD, 0, 0, 0);

  // q_linT via tiled transpose
  transpose_k<<<dim3(LQN / 64, HD / 64, NBATCH), 256, 0, stream>>>(qlin, qlinT);

  for (int c = 0; c < 2; ++c) {
    int bz0 = c * 8;
    gemm8p<0><<<dim3(LPN / 256, LQN / 256, 8), 512, SH, stream>>>(
        plin + (size_t)bz0 * LPN * HD, qlin + (size_t)bz0 * LQN * HD,
        (const float*)0, scores,
        /*K=*/HD, /*lda=*/HD, /*ldb=*/HD, /*ldc=*/LQN,
        (long)LPN * HD, (long)LQN * HD, (long)LPN * LQN);
    softmax_k<<<8 * LPN, 256, 0, stream>>>(scores);
    gemm8p<0><<<dim3(LPN / 256, HD / 256, 8), 512, SH, stream>>>(
        (const _Float16*)scores, qlinT + (size_t)bz0 * HD * LQN,
        (const float*)0, out + (size_t)bz0 * LPN * HD,
        /*K=*/LQN, /*lda=*/2 * LQN, /*ldb=*/LQN, /*ldc=*/HD,
        (long)LPN * 2 * LQN, (long)HD * LQN, (long)LPN * HD);
  }
}

// Round 6
// 590.324 us; speedup vs baseline: 1.0137x; 1.0137x over previous
//
#include <hip/hip_runtime.h>

// B=16, LQ=LP=2048, H=1024
//   q_lin = relu(q @ W^T + b); p_lin = relu(p @ W^T + b)
//   scores = p_lin @ q_lin^T ; att = softmax(scores); out = att @ q_lin
// GEMMs: 256x256 tile, BK=64, 8 waves, 8-phase schedule, fp16 MFMA 16x16x32.
// Round-6: (1) N-fast + XCD-chunked block mapping (A-panel L2 reuse);
// (2) scores epilogue emits P_t=exp(s-m_t) fp16 + (m_t,sum_t) side buffer;
// renorm_k folds global softmax scale into P; PV reads dense fp16 P.

#define LQN 2048
#define LPN 2048
#define HD  1024
#define NBATCH 16

typedef _Float16 half8 __attribute__((ext_vector_type(8)));
typedef _Float16 half4_t __attribute__((ext_vector_type(4)));
typedef float f32x4 __attribute__((ext_vector_type(4)));

#define GLP(src, dst) __builtin_amdgcn_global_load_lds(                          \
    (const __attribute__((address_space(1))) void*)(src),                        \
    (__attribute__((address_space(3))) void*)(dst), 16, 0, 0)

// ---------------------------------------------------------------- convert f32->f16
__global__ __launch_bounds__(256) void cvt_f32_f16(const float* __restrict__ in,
                                                   _Float16* __restrict__ out,
                                                   long n4) {
  long i0 = (long)blockIdx.x * blockDim.x + threadIdx.x;
  long stride = (long)gridDim.x * blockDim.x;
  for (long i = i0; i < n4; i += stride) {
    float4 v = ((const float4*)in)[i];
    half4_t h = {(_Float16)v.x, (_Float16)v.y, (_Float16)v.z, (_Float16)v.w};
    ((half4_t*)out)[i] = h;
  }
}

// ---------------------------------------------------------------- tiled transpose
__global__ __launch_bounds__(256) void transpose_k(const _Float16* __restrict__ in,
                                                   _Float16* __restrict__ out) {
  __shared__ _Float16 t[64][72];
  const int bz = blockIdx.z;
  const int q0 = blockIdx.x * 64;
  const int d0 = blockIdx.y * 64;
  const int tt = threadIdx.x;
  const int ql = tt & 63, dg = tt >> 6;
  const _Float16* src = in + ((size_t)bz * LQN + q0 + ql) * HD + d0 + dg * 16;
  half8 v0 = *(const half8*)(src);
  half8 v1 = *(const half8*)(src + 8);
  int g0 = (dg * 2) ^ (ql & 7);
  int g1 = (dg * 2 + 1) ^ (ql & 7);
  *(half8*)&t[ql][g0 * 8] = v0;
  *(half8*)&t[ql][g1 * 8] = v1;
  __syncthreads();
  const int dl = tt & 63, qg = tt >> 6;
  half8 o0, o1;
#pragma unroll
  for (int j = 0; j < 8; ++j) {
    int qq = qg * 16 + j;
    o0[j] = t[qq][(((dl >> 3) ^ (qq & 7)) << 3) + (dl & 7)];
  }
#pragma unroll
  for (int j = 0; j < 8; ++j) {
    int qq = qg * 16 + 8 + j;
    o1[j] = t[qq][(((dl >> 3) ^ (qq & 7)) << 3) + (dl & 7)];
  }
  _Float16* dst = out + ((size_t)bz * HD + d0 + dl) * LQN + q0 + qg * 16;
  *(half8*)dst = o0;
  *(half8*)(dst + 8) = o1;
}

// ---------------------------------------------------------------- 8-phase 256^2 GEMM
// EPI 0: f32 C (+z*sCz).  EPI 1: fp16 C = relu(acc+bias).
// EPI 2: fp16 P_t = exp(s - m_t) per 256-col tile + side (m_t, sum_t).

#define SYNC_PRE                                        \
  __builtin_amdgcn_sched_barrier(0);                    \
  __builtin_amdgcn_s_barrier();                         \
  asm volatile("s_waitcnt lgkmcnt(0)" ::: "memory");    \
  __builtin_amdgcn_sched_barrier(0);                    \
  __builtin_amdgcn_s_setprio(1);

#define SYNC_POST                                       \
  __builtin_amdgcn_s_setprio(0);                        \
  __builtin_amdgcn_sched_barrier(0);                    \
  __builtin_amdgcn_s_barrier();

#define SYNC_POST_VM                                    \
  __builtin_amdgcn_s_setprio(0);                        \
  __builtin_amdgcn_sched_barrier(0);                    \
  asm volatile("s_waitcnt vmcnt(4)" ::: "memory");      \
  __builtin_amdgcn_s_barrier();

#define LOADA(qm, buf)                                                            \
  _Pragma("unroll")                                                               \
  for (int mi = 0; mi < 4; ++mi) {                                                \
    areg[mi][0] = *(const half8*)(smA + (buf)*32768 + a0 + ((qm)*4+mi)*4096);     \
    areg[mi][1] = *(const half8*)(smA + (buf)*32768 + a1 + ((qm)*4+mi)*4096);     \
  }

#define LOADB(qn, buf)                                                            \
  _Pragma("unroll")                                                               \
  for (int ni = 0; ni < 2; ++ni) {                                                \
    bregs[qn][ni][0] = *(const half8*)(smB + (buf)*32768 + b0 + ((qn)*2+ni)*8192);\
    bregs[qn][ni][1] = *(const half8*)(smB + (buf)*32768 + b1 + ((qn)*2+ni)*8192);\
  }

#define STAGEA(t, h, buf) do {                                                    \
  GLP(gA + (size_t)((h)*128)*lda + (size_t)(t)*64,                                \
      smW + (buf)*32768 + (h)*16384 + wid*1024);                                  \
  GLP(gA + (size_t)((h)*128+64)*lda + (size_t)(t)*64,                             \
      smW + (buf)*32768 + (h)*16384 + 8192 + wid*1024);                           \
} while (0)

#define STAGEB(t, h, buf) do {                                                    \
  GLP(gB + (size_t)((h)*128)*ldb + (size_t)(t)*64,                                \
      smW + 65536 + (buf)*32768 + (h)*16384 + wid*1024);                          \
  GLP(gB + (size_t)((h)*128+64)*ldb + (size_t)(t)*64,                             \
      smW + 65536 + (buf)*32768 + (h)*16384 + 8192 + wid*1024);                   \
} while (0)

#define DO_MFMA(qm, qn)                                                           \
  _Pragma("unroll")                                                               \
  for (int mi = 0; mi < 4; ++mi) {                                                \
    _Pragma("unroll")                                                             \
    for (int ni = 0; ni < 2; ++ni) {                                              \
      acc[(qm)*4+mi][(qn)*2+ni] = __builtin_amdgcn_mfma_f32_16x16x32_f16(         \
          areg[mi][0], bregs[qn][ni][0], acc[(qm)*4+mi][(qn)*2+ni], 0, 0, 0);     \
      acc[(qm)*4+mi][(qn)*2+ni] = __builtin_amdgcn_mfma_f32_16x16x32_f16(         \
          areg[mi][1], bregs[qn][ni][1], acc[(qm)*4+mi][(qn)*2+ni], 0, 0, 0);     \
    }                                                                             \
  }

template <int EPI>
__global__ __launch_bounds__(512, 2) void gemm8p(
    const _Float16* __restrict__ A, const _Float16* __restrict__ B,
    const float* __restrict__ bias, void* __restrict__ Cv,
    float2* __restrict__ side, int K, int lda, int ldb, int ldc,
    long sAz, long sBz, long sCz) {
  extern __shared__ __align__(16) char smem[];
  const char* smA = smem;
  const char* smB = smem + 65536;
  char* smW = smem;

  const int tid = threadIdx.x;
  const int lane = tid & 63, wid = tid >> 6;
  const int l16 = lane & 15, lhi = lane >> 4;
  const int wr = wid >> 2, wcn = wid & 3;

  // N-fast + XCD-chunked mapping: grid = (N-tiles, M-tiles, z).
  // dispatch id d round-robins over XCDs; give XCD k a contiguous tile chunk.
  const int nx = gridDim.x;
  const int d = blockIdx.y * nx + blockIdx.x;
  const int cpx = (nx * gridDim.y) >> 3;
  const int t_ = (d & 7) * cpx + (d >> 3);
  const int xsh = 31 - __builtin_clz(nx);
  const int bn0 = (t_ & (nx - 1)) << 8;
  const int bm0 = (t_ >> xsh) << 8;

  // swizzle: flip 16B-slot bits 4-6 by row bits 0-2
  const int mask = (l16 & 7) << 4;
  const int a0 = (wr * 2048 + l16 * 128 + lhi * 16) ^ mask;
  const int a1 = a0 ^ 64;
  const int b0 = (wcn * 2048 + l16 * 128 + lhi * 16) ^ mask;
  const int b1 = b0 ^ 64;

  const int srow = tid >> 3;
  const int scol = (((tid & 7) ^ ((tid >> 3) & 7)) << 3);

  const _Float16* gA = A + (size_t)blockIdx.z * sAz + (size_t)(bm0 + srow) * lda + scol;
  const _Float16* gB = B + (size_t)blockIdx.z * sBz + (size_t)(bn0 + srow) * ldb + scol;

  const int NT = K >> 6, NI = K >> 7;

  f32x4 acc[8][4] = {};
  half8 areg[4][2], bregs[2][2][2];

  STAGEA(0, 0, 0); STAGEB(0, 0, 0);
  STAGEA(0, 1, 0); STAGEB(0, 1, 0);
  STAGEA(1, 0, 1); STAGEB(1, 0, 1);
  __builtin_amdgcn_sched_barrier(0);
  asm volatile("s_waitcnt vmcnt(4)" ::: "memory");
  __builtin_amdgcn_s_barrier();

  for (int i = 0; i < NI; ++i) {
    const int t1 = 2 * i + 1;
    int t2 = 2 * i + 2; if (t2 > NT - 1) t2 = NT - 1;
    int t3 = 2 * i + 3; if (t3 > NT - 1) t3 = NT - 1;
    // ph1
    LOADA(0, 0) LOADB(0, 0) STAGEA(t1, 1, 1);
    SYNC_PRE DO_MFMA(0, 0) SYNC_POST
    // ph2
    LOADB(1, 0) STAGEB(t1, 1, 1);
    SYNC_PRE DO_MFMA(0, 1) SYNC_POST
    // ph3
    LOADA(1, 0) STAGEA(t2, 0, 0);
    SYNC_PRE DO_MFMA(1, 0) SYNC_POST
    // ph4
    STAGEB(t2, 0, 0);
    SYNC_PRE DO_MFMA(1, 1) SYNC_POST_VM
    // ph5
    LOADA(0, 1) LOADB(0, 1) STAGEA(t2, 1, 0);
    SYNC_PRE DO_MFMA(0, 0) SYNC_POST
    // ph6
    LOADB(1, 1) STAGEB(t2, 1, 0);
    SYNC_PRE DO_MFMA(0, 1) SYNC_POST
    // ph7
    LOADA(1, 1) STAGEA(t3, 0, 1);
    SYNC_PRE DO_MFMA(1, 0) SYNC_POST
    // ph8
    STAGEB(t3, 0, 1);
    SYNC_PRE DO_MFMA(1, 1) SYNC_POST_VM
  }

  if constexpr (EPI == 0) {
    float* Cb = (float*)Cv + (size_t)blockIdx.z * sCz;
#pragma unroll
    for (int m = 0; m < 8; ++m) {
      int row0 = bm0 + m * 32 + wr * 16 + lhi * 4;
#pragma unroll
      for (int n = 0; n < 4; ++n) {
        int col = bn0 + n * 64 + wcn * 16 + l16;
#pragma unroll
        for (int v = 0; v < 4; ++v)
          Cb[(size_t)(row0 + v) * ldc + col] = acc[m][n][v];
      }
    }
  } else if constexpr (EPI == 1) {
    _Float16* Cb = (_Float16*)Cv;
#pragma unroll
    for (int n = 0; n < 4; ++n) {
      int col = bn0 + n * 64 + wcn * 16 + l16;
      float bv = bias[col];
#pragma unroll
      for (int m = 0; m < 8; ++m) {
        int row0 = bm0 + m * 32 + wr * 16 + lhi * 4;
        Cb[(size_t)(row0 + 0) * ldc + col] = (_Float16)fmaxf(acc[m][n][0] + bv, 0.f);
        Cb[(size_t)(row0 + 1) * ldc + col] = (_Float16)fmaxf(acc[m][n][1] + bv, 0.f);
        Cb[(size_t)(row0 + 2) * ldc + col] = (_Float16)fmaxf(acc[m][n][2] + bv, 0.f);
        Cb[(size_t)(row0 + 3) * ldc + col] = (_Float16)fmaxf(acc[m][n][3] + bv, 0.f);
      }
    }
  } else {
    // EPI == 2: partial softmax over this block's 256 cols.
    // row r = m*32 + wr*16 + lhi*4 + v ; col = n*64 + wcn*16 + l16
    float* redm = (float*)smW;            // [256][4]
    float* reds = (float*)(smW + 4096);   // [256][4]
    float tm[8][4];
#pragma unroll
    for (int m = 0; m < 8; ++m)
#pragma unroll
      for (int v = 0; v < 4; ++v)
        tm[m][v] = fmaxf(fmaxf(acc[m][0][v], acc[m][1][v]),
                         fmaxf(acc[m][2][v], acc[m][3][v]));
#pragma unroll
    for (int o = 1; o < 16; o <<= 1)
#pragma unroll
      for (int m = 0; m < 8; ++m)
#pragma unroll
        for (int v = 0; v < 4; ++v)
          tm[m][v] = fmaxf(tm[m][v], __shfl_xor(tm[m][v], o));
    if (l16 == 0) {
#pragma unroll
      for (int m = 0; m < 8; ++m)
#pragma unroll
        for (int v = 0; v < 4; ++v)
          redm[(m * 32 + wr * 16 + lhi * 4 + v) * 4 + wcn] = tm[m][v];
    }
    __syncthreads();
    float rm[8][4], rs[8][4];
#pragma unroll
    for (int m = 0; m < 8; ++m)
#pragma unroll
      for (int v = 0; v < 4; ++v) {
        float4 q4 = ((const float4*)redm)[m * 32 + wr * 16 + lhi * 4 + v];
        rm[m][v] = fmaxf(fmaxf(q4.x, q4.y), fmaxf(q4.z, q4.w));
      }
    // exp in place, per-thread n-sum, cross-lane sum
#pragma unroll
    for (int m = 0; m < 8; ++m)
#pragma unroll
      for (int v = 0; v < 4; ++v) {
        float s = 0.f;
#pragma unroll
        for (int n = 0; n < 4; ++n) {
          float e = __expf(acc[m][n][v] - rm[m][v]);
          acc[m][n][v] = e;
          s += e;
        }
        tm[m][v] = s;
      }
#pragma unroll
    for (int o = 1; o < 16; o <<= 1)
#pragma unroll
      for (int m = 0; m < 8; ++m)
#pragma unroll
        for (int v = 0; v < 4; ++v)
          tm[m][v] += __shfl_xor(tm[m][v], o);
    __syncthreads();
    if (l16 == 0) {
#pragma unroll
      for (int m = 0; m < 8; ++m)
#pragma unroll
        for (int v = 0; v < 4; ++v)
          reds[(m * 32 + wr * 16 + lhi * 4 + v) * 4 + wcn] = tm[m][v];
    }
    __syncthreads();
#pragma unroll
    for (int m = 0; m < 8; ++m)
#pragma unroll
      for (int v = 0; v < 4; ++v) {
        float4 q4 = ((const float4*)reds)[m * 32 + wr * 16 + lhi * 4 + v];
        rs[m][v] = (q4.x + q4.y) + (q4.z + q4.w);
      }
    _Float16* Cb = (_Float16*)Cv + (size_t)blockIdx.z * sCz;
#pragma unroll
    for (int n = 0; n < 4; ++n) {
      int col = bn0 + n * 64 + wcn * 16 + l16;
#pragma unroll
      for (int m = 0; m < 8; ++m) {
        int row0 = bm0 + m * 32 + wr * 16 + lhi * 4;
        Cb[(size_t)(row0 + 0) * ldc + col] = (_Float16)acc[m][n][0];
        Cb[(size_t)(row0 + 1) * ldc + col] = (_Float16)acc[m][n][1];
        Cb[(size_t)(row0 + 2) * ldc + col] = (_Float16)acc[m][n][2];
        Cb[(size_t)(row0 + 3) * ldc + col] = (_Float16)acc[m][n][3];
      }
    }
    if (l16 == 0 && wcn == 0) {
      float2* sb = side + ((size_t)blockIdx.z * 2048 + bm0) * 8 + (bn0 >> 8);
#pragma unroll
      for (int m = 0; m < 8; ++m)
#pragma unroll
        for (int v = 0; v < 4; ++v) {
          int r = m * 32 + wr * 16 + lhi * 4 + v;
          sb[(size_t)r * 8] = make_float2(rm[m][v], rs[m][v]);
        }
    }
  }
}

// ---------------------------------------------------------------- global renorm
// one block per (row, batch): fold exp(m_t - m)/S into P in place.
__global__ __launch_bounds__(256) void renorm_k(_Float16* __restrict__ P,
                                                const float2* __restrict__ side) {
  const int row = blockIdx.x;
  const int bz = blockIdx.y;
  const float2* sd = side + ((size_t)bz * 2048 + row) * 8;
  float mt[8], st[8];
#pragma unroll
  for (int t = 0; t < 8; ++t) { float2 v = sd[t]; mt[t] = v.x; st[t] = v.y; }
  float m = mt[0];
#pragma unroll
  for (int t = 1; t < 8; ++t) m = fmaxf(m, mt[t]);
  float S = 0.f;
#pragma unroll
  for (int t = 0; t < 8; ++t) S += st[t] * __expf(mt[t] - m);
  const float inv = 1.f / S;
  const int tid = threadIdx.x;
  const float sc = __expf(mt[tid >> 5] - m) * inv;
  _Float16* p = P + (((size_t)bz * 2048 + row) * 2048) + tid * 8;
  half8 v = *(half8*)p;
#pragma unroll
  for (int j = 0; j < 8; ++j) v[j] = (_Float16)((float)v[j] * sc);
  *(half8*)p = v;
}

// ---------------------------------------------------------------- launch
extern "C" void kernel_launch(void* const* d_in, const int* in_sizes, int n_in,
                              void* d_out, int out_size, void* d_ws, size_t ws_size,
                              hipStream_t stream) {
  const float* q = (const float*)d_in[0];
  const float* p = (const float*)d_in[1];
  const float* W = (const float*)d_in[2];
  const float* bias = (const float*)d_in[3];
  float* out = (float*)d_out;
  char* ws = (char*)d_ws;

  // ws: [0,128MB) scratch: qf/pf during linear; later P fp16 (64MB) + side (1MB).
  // then qlin(64MB)+plin(64MB) contiguous, qlinT(64MB), W_f16(2MB).
  _Float16* qf    = (_Float16*)(ws);
  _Float16* pf    = (_Float16*)(ws + 67108864L);
  _Float16* qlin  = (_Float16*)(ws + 134217728L);
  _Float16* plin  = (_Float16*)(ws + 201326592L);
  _Float16* qlinT = (_Float16*)(ws + 268435456L);
  _Float16* Wf    = (_Float16*)(ws + 335544320L);
  _Float16* Pbuf  = (_Float16*)(ws);
  float2*   side  = (float2*)(ws + 67108864L);

  const long nQ = (long)NBATCH * LQN * HD;
  const size_t SH = 131072;

  cvt_f32_f16<<<2048, 256, 0, stream>>>(q, qf, nQ / 4);
  cvt_f32_f16<<<2048, 256, 0, stream>>>(p, pf, nQ / 4);
  cvt_f32_f16<<<64, 256, 0, stream>>>(W, Wf, (long)HD * HD / 4);

  // fused shared linear + relu over q|p (M=65536); grid (N=4, M=512)
  gemm8p<1><<<dim3(HD / 256, 2 * NBATCH * LQN / 256, 1), 512, SH, stream>>>(
      qf, Wf, bias, qlin, (float2*)0, HD, HD, HD, HD, 0, 0, 0);

  transpose_k<<<dim3(LQN / 64, HD / 64, NBATCH), 256, 0, stream>>>(qlin, qlinT);

  for (int c = 0; c < 2; ++c) {
    int bz0 = c * 8;
    // scores + partial softmax -> P_t fp16 + side ; grid (N=8, M=8, z=8)
    gemm8p<2><<<dim3(LQN / 256, LPN / 256, 8), 512, SH, stream>>>(
        plin + (size_t)bz0 * LPN * HD, qlin + (size_t)bz0 * LQN * HD,
        (const float*)0, Pbuf, side,
        /*K=*/HD, /*lda=*/HD, /*ldb=*/HD, /*ldc=*/LQN,
        (long)LPN * HD, (long)LQN * HD, (long)LPN * LQN);
    renorm_k<<<dim3(LPN, 8), 256, 0, stream>>>(Pbuf, side);
    // PV: out = P @ qlinT^T ; grid (N=4, M=8, z=8)
    gemm8p<0><<<dim3(HD / 256, LPN / 256, 8), 512, SH, stream>>>(
        Pbuf, qlinT + (size_t)bz0 * HD * LQN,
        (const float*)0, out + (size_t)bz0 * LPN * HD, (float2*)0,
        /*K=*/LQN, /*lda=*/LQN, /*ldb=*/LQN, /*ldc=*/HD,
        (long)LPN * LQN, (long)HD * LQN, (long)LPN * HD);
  }
}